// Round 3
// baseline (1089.193 us; speedup 1.0000x reference)
//
#include <hip/hip_runtime.h>
#include <hip/hip_bf16.h>

typedef __attribute__((ext_vector_type(8))) short bf16x8;
typedef __attribute__((ext_vector_type(4))) float f32x4;
typedef __attribute__((ext_vector_type(4))) _Float16 f16x4;
typedef __attribute__((ext_vector_type(4))) unsigned short u16x4;

#define B_ 2
#define S_ 2048
#define E_ 2048
#define H_ 16
#define D_ 128
#define ELEMS (B_*S_*E_)   // 8388608 elements of [B,S,2048]
#define WELEMS (E_*E_)     // 4194304 elements per weight matrix

__device__ __forceinline__ unsigned short f2bf(float x) {
  unsigned int u = __float_as_uint(x);
  u += 0x7fffu + ((u >> 16) & 1u);
  return (unsigned short)(u >> 16);
}

__device__ __forceinline__ void async_load16(const void* g, void* l) {
  __builtin_amdgcn_global_load_lds(
      (const __attribute__((address_space(1))) unsigned int*)g,
      (__attribute__((address_space(3))) unsigned int*)l, 16, 0, 0);
}

// f32 -> bf16 (RNE), vectorized x4. n4 = n/4.
__global__ __launch_bounds__(256)
void cvt_f32_bf16(const float* __restrict__ src, unsigned short* __restrict__ dst, int n4)
{
  const int i = blockIdx.x * 256 + threadIdx.x;
  if (i < n4) {
    const f32x4 v = ((const f32x4*)src)[i];
    u16x4 o;
    o.x = f2bf(v.x); o.y = f2bf(v.y); o.z = f2bf(v.z); o.w = f2bf(v.w);
    ((u16x4*)dst)[i] = o;
  }
}

// C[m][n] = sum_k A[m][k] * Bw[n][k]   (torch Linear / B^T layout), bf16 in,
// f32 accumulate, output bf16 or f32. m97-ladder structure (128x128, BK=32).
template<bool F32OUT>
__global__ __launch_bounds__(256)
void gemm_bt(const __hip_bfloat16* __restrict__ A,
             const __hip_bfloat16* __restrict__ Bw,
             void* __restrict__ C, int M, int N, int K)
{
  __shared__ __hip_bfloat16 As[128*32];
  __shared__ __hip_bfloat16 Bs[128*32];
  const int tid  = threadIdx.x;
  const int lane = tid & 63;
  const int w    = tid >> 6;
  const int m0 = blockIdx.y * 128;
  const int n0 = blockIdx.x * 128;
  const int wm = (w >> 1) * 64;
  const int wn = (w & 1) * 64;
  const int lrow = lane >> 2;        // staging: row within 16-row chunk
  const int lcol = (lane & 3) * 8;   // staging: col (8 bf16 = 16 B)
  const int fr = lane & 15;          // MFMA frag row
  const int fg = lane >> 4;          // MFMA frag k-group

  f32x4 acc[4][4];
#pragma unroll
  for (int i = 0; i < 4; i++)
#pragma unroll
    for (int j = 0; j < 4; j++) acc[i][j] = (f32x4)0.0f;

  for (int k0 = 0; k0 < K; k0 += 32) {
    __syncthreads();
#pragma unroll
    for (int s = 0; s < 2; s++) {
      const int rbase = s*64 + w*16;   // wave-uniform LDS base; HW adds lane*16B
      async_load16(A  + (size_t)(m0 + rbase + lrow)*K + k0 + lcol, As + rbase*32);
      async_load16(Bw + (size_t)(n0 + rbase + lrow)*K + k0 + lcol, Bs + rbase*32);
    }
    __syncthreads();
    bf16x8 af[4], bfr[4];
#pragma unroll
    for (int i = 0; i < 4; i++) {
      af[i]  = *(const bf16x8*)(As + (wm + i*16 + fr)*32 + fg*8);
      bfr[i] = *(const bf16x8*)(Bs + (wn + i*16 + fr)*32 + fg*8);
    }
#pragma unroll
    for (int i = 0; i < 4; i++)
#pragma unroll
      for (int j = 0; j < 4; j++)
        acc[i][j] = __builtin_amdgcn_mfma_f32_16x16x32_bf16(af[i], bfr[j], acc[i][j], 0, 0, 0);
  }

#pragma unroll
  for (int i = 0; i < 4; i++) {
    const int row = m0 + wm + i*16 + fg*4;
#pragma unroll
    for (int j = 0; j < 4; j++) {
      const int col = n0 + wn + j*16 + fr;
#pragma unroll
      for (int r = 0; r < 4; r++) {
        if (F32OUT) ((float*)C)[(size_t)(row + r)*N + col] = acc[i][j][r];
        else ((unsigned short*)C)[(size_t)(row + r)*N + col] = f2bf(acc[i][j][r]);
      }
    }
  }
}

// xpos rotary, in place on bf16 Q and K. One thread per (b,s,h,pair).
__global__ __launch_bounds__(256)
void xpos_rotary(__hip_bfloat16* __restrict__ Q, __hip_bfloat16* __restrict__ Kt)
{
  const int idx = blockIdx.x * 256 + threadIdx.x;   // [0, B*S*H*64)
  const int j = idx & 63;                            // pair index within head
  const int s = (idx >> 10) & 2047;                  // sequence position
  const float seq = (float)(s - 1024) * (1.0f/512.0f);
  const float dr = 2.0f + 2.0f*(float)j;
  const float theta = expf(dr * (1.0f/128.0f) * -9.210340371976184f);
  const float zeta  = (dr * (1.0f/64.0f) + 51.2f) * (1.0f/52.2f);
  const float ang = seq * theta;
  const float c  = cosf(ang);
  const float sn = sinf(ang);
  const float t  = expf(seq * logf(zeta));
  const float it = 1.0f / t;

  const size_t base = (size_t)(idx >> 6) * 128 + 2*j;
  unsigned short* Qs = (unsigned short*)Q;
  unsigned short* Ks = (unsigned short*)Kt;
  const float q0 = __bfloat162float(Q[base]),  q1 = __bfloat162float(Q[base+1]);
  Qs[base]   = f2bf((q0*c - q1*sn) * t);
  Qs[base+1] = f2bf((q1*c + q0*sn) * t);
  const float k0 = __bfloat162float(Kt[base]), k1 = __bfloat162float(Kt[base+1]);
  Ks[base]   = f2bf((k0*c - k1*sn) * it);
  Ks[base+1] = f2bf((k1*c + k0*sn) * it);
}

// V [B,S,H,D] bf16 -> VT [B,H,D,S] f16  (f16 for the 16x16x16f16 PV MFMA)
__global__ __launch_bounds__(256)
void transpose_v(const __hip_bfloat16* __restrict__ V, _Float16* __restrict__ VT)
{
  __shared__ float tile[32][33];
  const int tx = threadIdx.x, ty = threadIdx.y;      // block (32, 8)
  const int bh = blockIdx.z;
  const int b = bh >> 4, h = bh & 15;
  const int s0 = blockIdx.x * 32, d0 = blockIdx.y * 32;
#pragma unroll
  for (int r = 0; r < 4; r++) {
    const int s = s0 + ty + r*8;
    tile[ty + r*8][tx] = __bfloat162float(V[((size_t)(b*S_ + s))*E_ + h*D_ + d0 + tx]);
  }
  __syncthreads();
#pragma unroll
  for (int r = 0; r < 4; r++) {
    const int d = d0 + ty + r*8;
    VT[((size_t)(bh*D_ + d))*S_ + s0 + tx] = (_Float16)tile[tx][ty + r*8];
  }
}

// Flash attention, causal, 64-key tiles with cooperative LDS K staging.
// S^T = K*Q^T per 16-key subtile so the QK C-layout (row=key,col=q) is
// directly the B-operand layout of the 16x16x16f16 PV MFMA. One online-
// softmax pass per 64 keys. K tile chunk-XOR-swizzled in LDS so both the
// wave-uniform global_load_lds staging and the ds_read_b128 fragment reads
// work conflict-free.
__global__ __launch_bounds__(256)
void attn_fwd(const __hip_bfloat16* __restrict__ Q,
              const __hip_bfloat16* __restrict__ K,
              const _Float16* __restrict__ VT,
              __hip_bfloat16* __restrict__ O)
{
  __shared__ float smem_f[64*128];                 // 32 KB; first 16 KB = K tile
  __hip_bfloat16* Ks = (__hip_bfloat16*)smem_f;    // [64 keys][128 d], 16B-chunk swizzled

  const int lane = threadIdx.x & 63;
  const int w    = threadIdx.x >> 6;
  const int bh = blockIdx.y;
  const int b = bh >> 4, h = bh & 15;
  const int x  = blockIdx.x;
  const int q0 = x*64 + w*16;            // this wave's 16 q rows
  const int qc = lane & 15;              // q column owned by this lane
  const int g  = lane >> 4;              // k-group

  const size_t bh_base = (size_t)b*S_*E_ + h*D_;
  bf16x8 qf[4];
  {
    const __hip_bfloat16* qrow = Q + bh_base + (size_t)(q0 + qc)*E_ + g*8;
#pragma unroll
    for (int c = 0; c < 4; c++) qf[c] = *(const bf16x8*)(qrow + c*32);
  }
  const _Float16* vt = VT + (size_t)bh*D_*S_;

  // staging decomposition: linear 16B chunk cid = (w*4+i)*64 + lane;
  // key = cid>>4, lds-chunk = cid&15, global-chunk = (cid&15) ^ (key&15)
  const __hip_bfloat16* kptr[4];
  unsigned int ldsoff[4];
#pragma unroll
  for (int i = 0; i < 4; i++) {
    const int cid = (w*4+i)*64 + lane;
    const int key = cid >> 4;
    const int cg  = (cid & 15) ^ (key & 15);
    kptr[i] = K + bh_base + (size_t)key*E_ + cg*8;
    ldsoff[i] = (w*4+i)*64*8;      // elements; wave-uniform
  }

  f32x4 acc_o[8];
#pragma unroll
  for (int t = 0; t < 8; t++) acc_o[t] = (f32x4)0.0f;
  float m_i = -1e30f, l_i = 0.0f;
  const float scale = 0.08838834764831845f;   // 1/sqrt(128)

  const int ntiles = x + 1;                   // 64-key tiles (same for all 4 waves)
  for (int kt = 0; kt < ntiles; ++kt) {
    const int k0 = kt*64;
    __syncthreads();                          // previous tile fully consumed
#pragma unroll
    for (int i = 0; i < 4; i++)
      async_load16(kptr[i] + (size_t)k0*E_, Ks + ldsoff[i]);
    __syncthreads();                          // staging drained (vmcnt(0) at barrier)

    const int nsub = (kt == ntiles-1) ? (w+1) : 4;   // causal: skip all-masked subtiles

    float sv[16];
#pragma unroll
    for (int ts = 0; ts < 4; ts++) {
      if (ts < nsub) {
        f32x4 sacc = (f32x4)0.0f;
#pragma unroll
        for (int c = 0; c < 4; c++) {
          const bf16x8 kf = *(const bf16x8*)(Ks + (ts*16 + qc)*128 + (((c*4+g) ^ qc)*8));
          sacc = __builtin_amdgcn_mfma_f32_16x16x32_bf16(kf, qf[c], sacc, 0, 0, 0);
        }
#pragma unroll
        for (int r = 0; r < 4; r++) {
          const int key = k0 + ts*16 + g*4 + r;
          sv[ts*4+r] = (key <= q0 + qc) ? sacc[r]*scale : -1e30f;
        }
      } else {
#pragma unroll
        for (int r = 0; r < 4; r++) sv[ts*4+r] = -1e30f;
      }
    }

    // one online-softmax pass per 64 keys
    float mx = sv[0];
#pragma unroll
    for (int j = 1; j < 16; j++) mx = fmaxf(mx, sv[j]);
    mx = fmaxf(mx, __shfl_xor(mx, 16));
    mx = fmaxf(mx, __shfl_xor(mx, 32));
    const float m_new = fmaxf(m_i, mx);
    const float alpha = __expf(m_i - m_new);
    float p[16], ps = 0.0f;
#pragma unroll
    for (int j = 0; j < 16; j++) { p[j] = __expf(sv[j] - m_new); ps += p[j]; }
    ps += __shfl_xor(ps, 16);
    ps += __shfl_xor(ps, 32);
    l_i = l_i*alpha + ps;
    m_i = m_new;

    f16x4 pf[4];
#pragma unroll
    for (int ts = 0; ts < 4; ts++)
#pragma unroll
      for (int r = 0; r < 4; r++) pf[ts][r] = (_Float16)p[ts*4+r];

#pragma unroll
    for (int t = 0; t < 8; t++) acc_o[t] *= alpha;
#pragma unroll
    for (int ts = 0; ts < 4; ts++) {
      if (ts < nsub) {
#pragma unroll
        for (int t = 0; t < 8; t++) {
          const f16x4 vf = *(const f16x4*)(vt + (size_t)(t*16 + qc)*S_ + k0 + ts*16 + g*4);
          acc_o[t] = __builtin_amdgcn_mfma_f32_16x16x16f16(vf, pf[ts], acc_o[t], 0, 0, 0);
        }
      }
    }
  }

  // epilogue: O^T[d][q] -> LDS as O[q][d], then coalesced bf16 store
  __syncthreads();                            // all waves done reading Ks
  const float inv_l = 1.0f / l_i;
#pragma unroll
  for (int t = 0; t < 8; t++)
#pragma unroll
    for (int r = 0; r < 4; r++)
      smem_f[(w*16 + qc)*128 + t*16 + g*4 + r] = acc_o[t][r] * inv_l;
  __syncthreads();

  const int row = threadIdx.x >> 2;          // 0..63
  const int c0  = (threadIdx.x & 3) * 32;
  unsigned short* Os = (unsigned short*)O;
  const size_t obase = bh_base + (size_t)(x*64 + row)*E_;
#pragma unroll
  for (int i = 0; i < 8; i++) {
    const f32x4 v4 = *(const f32x4*)(smem_f + row*128 + c0 + i*4);
    u16x4 o4;
    o4.x = f2bf(v4.x); o4.y = f2bf(v4.y); o4.z = f2bf(v4.z); o4.w = f2bf(v4.w);
    *(u16x4*)(Os + obase + c0 + i*4) = o4;
  }
}

extern "C" void kernel_launch(void* const* d_in, const int* in_sizes, int n_in,
                              void* d_out, int out_size, void* d_ws, size_t ws_size,
                              hipStream_t stream)
{
  (void)in_sizes; (void)n_in; (void)out_size; (void)ws_size;
  // Inputs are float32 per the reference dtypes.
  const float* act = (const float*)d_in[0];
  const float* Wq  = (const float*)d_in[1];
  const float* Wk  = (const float*)d_in[2];
  const float* Wv  = (const float*)d_in[3];
  const float* Wo  = (const float*)d_in[4];

  // workspace layout (112 MB):
  // actb(16) Wqb(8) Wkb(8) Wvb(8) Wob(8) Q(16) K(16) V/AO(16) VT(16)
  __hip_bfloat16* actb = (__hip_bfloat16*)d_ws;
  __hip_bfloat16* Wqb  = actb + ELEMS;
  __hip_bfloat16* Wkb  = Wqb + WELEMS;
  __hip_bfloat16* Wvb  = Wkb + WELEMS;
  __hip_bfloat16* Wob  = Wvb + WELEMS;
  __hip_bfloat16* Q    = Wob + WELEMS;
  __hip_bfloat16* Kp   = Q + ELEMS;
  __hip_bfloat16* V    = Kp + ELEMS;
  _Float16*       VT   = (_Float16*)(V + ELEMS);
  __hip_bfloat16* AO   = V;   // V dead after transpose_v; reuse for attn output

  cvt_f32_bf16<<<ELEMS/4/256,  256, 0, stream>>>(act, (unsigned short*)actb, ELEMS/4);
  cvt_f32_bf16<<<WELEMS/4/256, 256, 0, stream>>>(Wq,  (unsigned short*)Wqb,  WELEMS/4);
  cvt_f32_bf16<<<WELEMS/4/256, 256, 0, stream>>>(Wk,  (unsigned short*)Wkb,  WELEMS/4);
  cvt_f32_bf16<<<WELEMS/4/256, 256, 0, stream>>>(Wv,  (unsigned short*)Wvb,  WELEMS/4);
  cvt_f32_bf16<<<WELEMS/4/256, 256, 0, stream>>>(Wo,  (unsigned short*)Wob,  WELEMS/4);

  const dim3 gg(E_/128, (B_*S_)/128);
  gemm_bt<false><<<gg, 256, 0, stream>>>(actb, Wqb, Q,  B_*S_, E_, E_);
  gemm_bt<false><<<gg, 256, 0, stream>>>(actb, Wkb, Kp, B_*S_, E_, E_);
  gemm_bt<false><<<gg, 256, 0, stream>>>(actb, Wvb, V,  B_*S_, E_, E_);
  xpos_rotary<<<(B_*S_*H_*64)/256, 256, 0, stream>>>(Q, Kp);
  transpose_v<<<dim3(S_/32, D_/32, B_*H_), dim3(32, 8), 0, stream>>>(V, VT);
  attn_fwd<<<dim3(S_/64, B_*H_), 256, 0, stream>>>(Q, Kp, VT, AO);
  gemm_bt<true><<<gg, 256, 0, stream>>>(AO, Wob, d_out, B_*S_, E_, E_);
}

// Round 4
// 1051.646 us; speedup vs baseline: 1.0357x; 1.0357x over previous
//
#include <hip/hip_runtime.h>
#include <hip/hip_bf16.h>

typedef __attribute__((ext_vector_type(8))) short bf16x8;
typedef __attribute__((ext_vector_type(4))) float f32x4;
typedef __attribute__((ext_vector_type(4))) _Float16 f16x4;
typedef __attribute__((ext_vector_type(4))) unsigned short u16x4;

#define B_ 2
#define S_ 2048
#define E_ 2048
#define H_ 16
#define D_ 128
#define ELEMS (B_*S_*E_)   // 8388608 elements of [B,S,2048]
#define WELEMS (E_*E_)     // 4194304 elements per weight matrix

__device__ __forceinline__ unsigned short f2bf(float x) {
  unsigned int u = __float_as_uint(x);
  u += 0x7fffu + ((u >> 16) & 1u);
  return (unsigned short)(u >> 16);
}

__device__ __forceinline__ void async_load16(const void* g, void* l) {
  __builtin_amdgcn_global_load_lds(
      (const __attribute__((address_space(1))) unsigned int*)g,
      (__attribute__((address_space(3))) unsigned int*)l, 16, 0, 0);
}

// f32 -> bf16 (RNE), vectorized x4. n4 = n/4.
__global__ __launch_bounds__(256)
void cvt_f32_bf16(const float* __restrict__ src, unsigned short* __restrict__ dst, int n4)
{
  const int i = blockIdx.x * 256 + threadIdx.x;
  if (i < n4) {
    const f32x4 v = ((const f32x4*)src)[i];
    u16x4 o;
    o.x = f2bf(v.x); o.y = f2bf(v.y); o.z = f2bf(v.z); o.w = f2bf(v.w);
    ((u16x4*)dst)[i] = o;
  }
}

// C[m][n] = sum_k A[m][k] * Bw[n][k]   (torch Linear / B^T layout), bf16 in,
// f32 accumulate. OUTMODE: 0 = bf16 row-major, 1 = f32 row-major,
// 2 = bf16 head-major [b, h, s, d] (row=b*2048+s, col=h*128+d).
template<int OUTMODE>
__global__ __launch_bounds__(256)
void gemm_bt(const __hip_bfloat16* __restrict__ A,
             const __hip_bfloat16* __restrict__ Bw,
             void* __restrict__ C, int M, int N, int K)
{
  __shared__ __hip_bfloat16 As[128*32];
  __shared__ __hip_bfloat16 Bs[128*32];
  const int tid  = threadIdx.x;
  const int lane = tid & 63;
  const int w    = tid >> 6;
  const int m0 = blockIdx.y * 128;
  const int n0 = blockIdx.x * 128;
  const int wm = (w >> 1) * 64;
  const int wn = (w & 1) * 64;
  const int lrow = lane >> 2;        // staging: row within 16-row chunk
  const int lcol = (lane & 3) * 8;   // staging: col (8 bf16 = 16 B)
  const int fr = lane & 15;          // MFMA frag row
  const int fg = lane >> 4;          // MFMA frag k-group

  f32x4 acc[4][4];
#pragma unroll
  for (int i = 0; i < 4; i++)
#pragma unroll
    for (int j = 0; j < 4; j++) acc[i][j] = (f32x4)0.0f;

  for (int k0 = 0; k0 < K; k0 += 32) {
    __syncthreads();
#pragma unroll
    for (int s = 0; s < 2; s++) {
      const int rbase = s*64 + w*16;   // wave-uniform LDS base; HW adds lane*16B
      async_load16(A  + (size_t)(m0 + rbase + lrow)*K + k0 + lcol, As + rbase*32);
      async_load16(Bw + (size_t)(n0 + rbase + lrow)*K + k0 + lcol, Bs + rbase*32);
    }
    __syncthreads();
    bf16x8 af[4], bfr[4];
#pragma unroll
    for (int i = 0; i < 4; i++) {
      af[i]  = *(const bf16x8*)(As + (wm + i*16 + fr)*32 + fg*8);
      bfr[i] = *(const bf16x8*)(Bs + (wn + i*16 + fr)*32 + fg*8);
    }
#pragma unroll
    for (int i = 0; i < 4; i++)
#pragma unroll
      for (int j = 0; j < 4; j++)
        acc[i][j] = __builtin_amdgcn_mfma_f32_16x16x32_bf16(af[i], bfr[j], acc[i][j], 0, 0, 0);
  }

#pragma unroll
  for (int i = 0; i < 4; i++) {
    const int row = m0 + wm + i*16 + fg*4;
#pragma unroll
    for (int j = 0; j < 4; j++) {
      const int col = n0 + wn + j*16 + fr;
#pragma unroll
      for (int r = 0; r < 4; r++) {
        if (OUTMODE == 1) {
          ((float*)C)[(size_t)(row + r)*N + col] = acc[i][j][r];
        } else if (OUTMODE == 0) {
          ((unsigned short*)C)[(size_t)(row + r)*N + col] = f2bf(acc[i][j][r]);
        } else {
          // head-major [b,h,s,d]
          const int rr = row + r;
          const int b = rr >> 11, s = rr & 2047;
          const int h = col >> 7, d = col & 127;
          ((unsigned short*)C)[(((size_t)(b*H_ + h) << 11) + s)*D_ + d] = f2bf(acc[i][j][r]);
        }
      }
    }
  }
}

// xpos rotary, in place on head-major bf16 Q and K [b,h,s,d].
// idx>>6 = row index ((b*16+h)*2048 + s) -> s = (idx>>6)&2047.
__global__ __launch_bounds__(256)
void xpos_rotary(__hip_bfloat16* __restrict__ Q, __hip_bfloat16* __restrict__ Kt)
{
  const int idx = blockIdx.x * 256 + threadIdx.x;   // [0, B*H*S*64)
  const int j = idx & 63;                            // pair index within head
  const int s = (idx >> 6) & 2047;                   // sequence position
  const float seq = (float)(s - 1024) * (1.0f/512.0f);
  const float dr = 2.0f + 2.0f*(float)j;
  const float theta = expf(dr * (1.0f/128.0f) * -9.210340371976184f);
  const float zeta  = (dr * (1.0f/64.0f) + 51.2f) * (1.0f/52.2f);
  const float ang = seq * theta;
  const float c  = cosf(ang);
  const float sn = sinf(ang);
  const float t  = expf(seq * logf(zeta));
  const float it = 1.0f / t;

  const size_t base = (size_t)(idx >> 6) * 128 + 2*j;
  unsigned short* Qs = (unsigned short*)Q;
  unsigned short* Ks = (unsigned short*)Kt;
  const float q0 = __bfloat162float(Q[base]),  q1 = __bfloat162float(Q[base+1]);
  Qs[base]   = f2bf((q0*c - q1*sn) * t);
  Qs[base+1] = f2bf((q1*c + q0*sn) * t);
  const float k0 = __bfloat162float(Kt[base]), k1 = __bfloat162float(Kt[base+1]);
  Ks[base]   = f2bf((k0*c - k1*sn) * it);
  Ks[base+1] = f2bf((k1*c + k0*sn) * it);
}

// Vh [b,h,s,d] bf16 -> VT3 [bh][kt=s/64][d][s%64] f16 (16-KB contiguous tiles)
__global__ __launch_bounds__(256)
void transpose_v(const __hip_bfloat16* __restrict__ Vh, _Float16* __restrict__ VT3)
{
  __shared__ float tile[32][33];
  const int tx = threadIdx.x, ty = threadIdx.y;      // block (32, 8)
  const int bh = blockIdx.z;
  const int s0 = blockIdx.x * 32, d0 = blockIdx.y * 32;
  const int kt = s0 >> 6, koff = s0 & 63;
#pragma unroll
  for (int r = 0; r < 4; r++) {
    const int s = s0 + ty + r*8;
    tile[ty + r*8][tx] = __bfloat162float(Vh[((size_t)bh*S_ + s)*D_ + d0 + tx]);
  }
  __syncthreads();
#pragma unroll
  for (int r = 0; r < 4; r++) {
    const int d = d0 + ty + r*8;
    VT3[(((size_t)bh*32 + kt)*D_ + d)*64 + koff + tx] = (_Float16)tile[tx][ty + r*8];
  }
}

// Flash attention, causal. Independent waves (no main-loop barriers), ILP-2:
// two 16-key tiles per iteration with one merged online-softmax pass.
// Head-major Q/K (16-key K tile = contiguous 4 KB); V in packed 16-KB
// [bh][kt][d][64] f16 tiles. S^T = K*Q^T so the QK C-layout (row=key,col=q)
// is directly the B-operand layout of the 16x16x16f16 PV MFMA.
// Longest blocks dispatched first (x = gridDim.x-1-blockIdx.x).
__global__ __launch_bounds__(256)
void attn_fwd(const __hip_bfloat16* __restrict__ Qh,
              const __hip_bfloat16* __restrict__ Kh,
              const _Float16* __restrict__ VT3,
              __hip_bfloat16* __restrict__ O)
{
  __shared__ float smem_f[64*128];     // 32 KB, epilogue transpose only
  const int lane = threadIdx.x & 63;
  const int w    = threadIdx.x >> 6;
  const int bh = blockIdx.y;
  const int b = bh >> 4, h = bh & 15;
  const int x  = gridDim.x - 1 - blockIdx.x;   // longest-first
  const int q0 = x*64 + w*16;          // this wave's 16 q rows
  const int qc = lane & 15;            // q column owned by this lane
  const int g  = lane >> 4;            // k-group
  const int qv = q0 + qc;

  const __hip_bfloat16* Kb = Kh + (size_t)bh*S_*D_;
  const _Float16* vtb = VT3 + (size_t)bh*32*D_*64;

  bf16x8 qf[4];
  {
    const __hip_bfloat16* qrow = Qh + ((size_t)bh*S_ + qv)*D_ + g*8;
#pragma unroll
    for (int c = 0; c < 4; c++) qf[c] = *(const bf16x8*)(qrow + c*32);
  }

  f32x4 acc_o[8];
#pragma unroll
  for (int t = 0; t < 8; t++) acc_o[t] = (f32x4)0.0f;
  float m_i = -1e30f, l_i = 0.0f;
  const float scale = 0.08838834764831845f;   // 1/sqrt(128)

  const int nt = x*4 + w + 1;          // 16-key tiles for this wave
  int kt = 0;
  for (; kt + 2 <= nt; kt += 2) {
    const __hip_bfloat16* krA = Kb + (size_t)(kt*16      + qc)*D_ + g*8;
    const __hip_bfloat16* krB = Kb + (size_t)(kt*16 + 16 + qc)*D_ + g*8;
    bf16x8 kfA[4], kfB[4];
#pragma unroll
    for (int c = 0; c < 4; c++) {
      kfA[c] = *(const bf16x8*)(krA + c*32);
      kfB[c] = *(const bf16x8*)(krB + c*32);
    }
    const _Float16* vA = vtb + (size_t)((kt  ) >> 2)*(D_*64) + ((kt  ) & 3)*16;
    const _Float16* vB = vtb + (size_t)((kt+1) >> 2)*(D_*64) + ((kt+1) & 3)*16;
    f16x4 vfA[8], vfB[8];
#pragma unroll
    for (int t = 0; t < 8; t++) {
      vfA[t] = *(const f16x4*)(vA + (t*16 + qc)*64 + g*4);
      vfB[t] = *(const f16x4*)(vB + (t*16 + qc)*64 + g*4);
    }

    f32x4 sA = (f32x4)0.0f, sB = (f32x4)0.0f;
#pragma unroll
    for (int c = 0; c < 4; c++) {
      sA = __builtin_amdgcn_mfma_f32_16x16x32_bf16(kfA[c], qf[c], sA, 0, 0, 0);
      sB = __builtin_amdgcn_mfma_f32_16x16x32_bf16(kfB[c], qf[c], sB, 0, 0, 0);
    }
    float sv[8];
#pragma unroll
    for (int r = 0; r < 4; r++) {
      sv[r]   = (kt*16      + g*4 + r <= qv) ? sA[r]*scale : -1e30f;
      sv[4+r] = (kt*16 + 16 + g*4 + r <= qv) ? sB[r]*scale : -1e30f;
    }
    float mx = sv[0];
#pragma unroll
    for (int j = 1; j < 8; j++) mx = fmaxf(mx, sv[j]);
    mx = fmaxf(mx, __shfl_xor(mx, 16));
    mx = fmaxf(mx, __shfl_xor(mx, 32));
    const float m_new = fmaxf(m_i, mx);
    const float alpha = __expf(m_i - m_new);
    float p[8], ps = 0.0f;
#pragma unroll
    for (int j = 0; j < 8; j++) { p[j] = __expf(sv[j] - m_new); ps += p[j]; }
    ps += __shfl_xor(ps, 16);
    ps += __shfl_xor(ps, 32);
    l_i = l_i*alpha + ps;
    m_i = m_new;
    f16x4 pA, pB;
#pragma unroll
    for (int r = 0; r < 4; r++) { pA[r] = (_Float16)p[r]; pB[r] = (_Float16)p[4+r]; }
#pragma unroll
    for (int t = 0; t < 8; t++) acc_o[t] *= alpha;
#pragma unroll
    for (int t = 0; t < 8; t++) {
      acc_o[t] = __builtin_amdgcn_mfma_f32_16x16x16f16(vfA[t], pA, acc_o[t], 0, 0, 0);
      acc_o[t] = __builtin_amdgcn_mfma_f32_16x16x16f16(vfB[t], pB, acc_o[t], 0, 0, 0);
    }
  }
  if (kt < nt) {   // tail: single (diagonal) 16-key tile
    const __hip_bfloat16* kr = Kb + (size_t)(kt*16 + qc)*D_ + g*8;
    bf16x8 kf[4];
#pragma unroll
    for (int c = 0; c < 4; c++) kf[c] = *(const bf16x8*)(kr + c*32);
    const _Float16* vA = vtb + (size_t)(kt >> 2)*(D_*64) + (kt & 3)*16;
    f16x4 vf[8];
#pragma unroll
    for (int t = 0; t < 8; t++) vf[t] = *(const f16x4*)(vA + (t*16 + qc)*64 + g*4);
    f32x4 sA = (f32x4)0.0f;
#pragma unroll
    for (int c = 0; c < 4; c++)
      sA = __builtin_amdgcn_mfma_f32_16x16x32_bf16(kf[c], qf[c], sA, 0, 0, 0);
    float sv[4];
#pragma unroll
    for (int r = 0; r < 4; r++)
      sv[r] = (kt*16 + g*4 + r <= qv) ? sA[r]*scale : -1e30f;
    float mx = fmaxf(fmaxf(sv[0], sv[1]), fmaxf(sv[2], sv[3]));
    mx = fmaxf(mx, __shfl_xor(mx, 16));
    mx = fmaxf(mx, __shfl_xor(mx, 32));
    const float m_new = fmaxf(m_i, mx);
    const float alpha = __expf(m_i - m_new);
    float p[4], ps = 0.0f;
#pragma unroll
    for (int j = 0; j < 4; j++) { p[j] = __expf(sv[j] - m_new); ps += p[j]; }
    ps += __shfl_xor(ps, 16);
    ps += __shfl_xor(ps, 32);
    l_i = l_i*alpha + ps;
    m_i = m_new;
    f16x4 pf;
#pragma unroll
    for (int r = 0; r < 4; r++) pf[r] = (_Float16)p[r];
#pragma unroll
    for (int t = 0; t < 8; t++) {
      acc_o[t] *= alpha;
      acc_o[t] = __builtin_amdgcn_mfma_f32_16x16x16f16(vf[t], pf, acc_o[t], 0, 0, 0);
    }
  }

  // epilogue: O^T[d][q] -> LDS as O[q][d], then coalesced bf16 store (token-major)
  __syncthreads();
  const float inv_l = 1.0f / l_i;
#pragma unroll
  for (int t = 0; t < 8; t++)
#pragma unroll
    for (int r = 0; r < 4; r++)
      smem_f[(w*16 + qc)*128 + t*16 + g*4 + r] = acc_o[t][r] * inv_l;
  __syncthreads();

  const int row = threadIdx.x >> 2;          // 0..63
  const int c0  = (threadIdx.x & 3) * 32;
  unsigned short* Os = (unsigned short*)O;
  const size_t obase = ((size_t)b*S_ + x*64 + row)*E_ + h*D_;
#pragma unroll
  for (int i = 0; i < 8; i++) {
    const f32x4 v4 = *(const f32x4*)(smem_f + row*128 + c0 + i*4);
    u16x4 o4;
    o4.x = f2bf(v4.x); o4.y = f2bf(v4.y); o4.z = f2bf(v4.z); o4.w = f2bf(v4.w);
    *(u16x4*)(Os + obase + c0 + i*4) = o4;
  }
}

extern "C" void kernel_launch(void* const* d_in, const int* in_sizes, int n_in,
                              void* d_out, int out_size, void* d_ws, size_t ws_size,
                              hipStream_t stream)
{
  (void)in_sizes; (void)n_in; (void)out_size; (void)ws_size;
  const float* act = (const float*)d_in[0];
  const float* Wq  = (const float*)d_in[1];
  const float* Wk  = (const float*)d_in[2];
  const float* Wv  = (const float*)d_in[3];
  const float* Wo  = (const float*)d_in[4];

  // workspace layout (112 MB):
  // actb(16) Wqb(8) Wkb(8) Wvb(8) Wob(8) Q(16) K(16) V/AO(16) VT3(16)
  __hip_bfloat16* actb = (__hip_bfloat16*)d_ws;
  __hip_bfloat16* Wqb  = actb + ELEMS;
  __hip_bfloat16* Wkb  = Wqb + WELEMS;
  __hip_bfloat16* Wvb  = Wkb + WELEMS;
  __hip_bfloat16* Wob  = Wvb + WELEMS;
  __hip_bfloat16* Q    = Wob + WELEMS;
  __hip_bfloat16* Kp   = Q + ELEMS;
  __hip_bfloat16* V    = Kp + ELEMS;
  _Float16*       VT   = (_Float16*)(V + ELEMS);
  __hip_bfloat16* AO   = V;   // V dead after transpose_v; reuse for attn output

  cvt_f32_bf16<<<ELEMS/4/256,  256, 0, stream>>>(act, (unsigned short*)actb, ELEMS/4);
  cvt_f32_bf16<<<WELEMS/4/256, 256, 0, stream>>>(Wq,  (unsigned short*)Wqb,  WELEMS/4);
  cvt_f32_bf16<<<WELEMS/4/256, 256, 0, stream>>>(Wk,  (unsigned short*)Wkb,  WELEMS/4);
  cvt_f32_bf16<<<WELEMS/4/256, 256, 0, stream>>>(Wv,  (unsigned short*)Wvb,  WELEMS/4);
  cvt_f32_bf16<<<WELEMS/4/256, 256, 0, stream>>>(Wo,  (unsigned short*)Wob,  WELEMS/4);

  const dim3 gg(E_/128, (B_*S_)/128);
  gemm_bt<2><<<gg, 256, 0, stream>>>(actb, Wqb, Q,  B_*S_, E_, E_);   // head-major
  gemm_bt<2><<<gg, 256, 0, stream>>>(actb, Wkb, Kp, B_*S_, E_, E_);   // head-major
  gemm_bt<2><<<gg, 256, 0, stream>>>(actb, Wvb, V,  B_*S_, E_, E_);   // head-major
  xpos_rotary<<<(B_*S_*H_*64)/256, 256, 0, stream>>>(Q, Kp);
  transpose_v<<<dim3(S_/32, D_/32, B_*H_), dim3(32, 8), 0, stream>>>(V, VT);
  attn_fwd<<<dim3(S_/64, B_*H_), 256, 0, stream>>>(Q, Kp, VT, AO);
  gemm_bt<1><<<gg, 256, 0, stream>>>(AO, Wob, d_out, B_*S_, E_, E_);
}

// Round 5
// 829.142 us; speedup vs baseline: 1.3136x; 1.2684x over previous
//
#include <hip/hip_runtime.h>
#include <hip/hip_bf16.h>

typedef __attribute__((ext_vector_type(8))) short bf16x8;
typedef __attribute__((ext_vector_type(4))) float f32x4;
typedef __attribute__((ext_vector_type(4))) _Float16 f16x4;
typedef __attribute__((ext_vector_type(8))) _Float16 f16x8;
typedef __attribute__((ext_vector_type(4))) unsigned short u16x4;

#define B_ 2
#define S_ 2048
#define E_ 2048
#define H_ 16
#define D_ 128
#define ELEMS (B_*S_*E_)   // 8388608 elements of [B,S,2048]
#define WELEMS (E_*E_)     // 4194304 elements per weight matrix

__device__ __forceinline__ unsigned short f2bf(float x) {
  unsigned int u = __float_as_uint(x);
  u += 0x7fffu + ((u >> 16) & 1u);
  return (unsigned short)(u >> 16);
}

__device__ __forceinline__ void async_load16(const void* g, void* l) {
  __builtin_amdgcn_global_load_lds(
      (const __attribute__((address_space(1))) unsigned int*)g,
      (__attribute__((address_space(3))) unsigned int*)l, 16, 0, 0);
}

// f32 -> bf16 (RNE), vectorized x4. n4 = n/4.
__global__ __launch_bounds__(256)
void cvt_f32_bf16(const float* __restrict__ src, unsigned short* __restrict__ dst, int n4)
{
  const int i = blockIdx.x * 256 + threadIdx.x;
  if (i < n4) {
    const f32x4 v = ((const f32x4*)src)[i];
    u16x4 o;
    o.x = f2bf(v.x); o.y = f2bf(v.y); o.z = f2bf(v.z); o.w = f2bf(v.w);
    ((u16x4*)dst)[i] = o;
  }
}

// four equally-sized weight tensors in one launch (blockIdx.y selects)
__global__ __launch_bounds__(256)
void cvt4_f32_bf16(const float* __restrict__ s0, const float* __restrict__ s1,
                   const float* __restrict__ s2, const float* __restrict__ s3,
                   unsigned short* __restrict__ d0, unsigned short* __restrict__ d1,
                   unsigned short* __restrict__ d2, unsigned short* __restrict__ d3,
                   int n4)
{
  const int i = blockIdx.x * 256 + threadIdx.x;
  if (i >= n4) return;
  const float* s; unsigned short* d;
  switch (blockIdx.y) {
    case 0: s = s0; d = d0; break;
    case 1: s = s1; d = d1; break;
    case 2: s = s2; d = d2; break;
    default: s = s3; d = d3; break;
  }
  const f32x4 v = ((const f32x4*)s)[i];
  u16x4 o;
  o.x = f2bf(v.x); o.y = f2bf(v.y); o.z = f2bf(v.z); o.w = f2bf(v.w);
  ((u16x4*)d)[i] = o;
}

// C[m][n] = sum_k A[m][k] * Bw[n][k]   (torch Linear / B^T layout), bf16 in,
// f32 accumulate. OUTMODE: 0 = bf16 row-major, 1 = f32 row-major,
// 2 = bf16 head-major [b, h, s, d] (row=b*2048+s, col=h*128+d).
template<int OUTMODE>
__global__ __launch_bounds__(256)
void gemm_bt(const __hip_bfloat16* __restrict__ A,
             const __hip_bfloat16* __restrict__ Bw,
             void* __restrict__ C, int M, int N, int K)
{
  __shared__ __hip_bfloat16 As[128*32];
  __shared__ __hip_bfloat16 Bs[128*32];
  const int tid  = threadIdx.x;
  const int lane = tid & 63;
  const int w    = tid >> 6;
  const int m0 = blockIdx.y * 128;
  const int n0 = blockIdx.x * 128;
  const int wm = (w >> 1) * 64;
  const int wn = (w & 1) * 64;
  const int lrow = lane >> 2;
  const int lcol = (lane & 3) * 8;
  const int fr = lane & 15;
  const int fg = lane >> 4;

  f32x4 acc[4][4];
#pragma unroll
  for (int i = 0; i < 4; i++)
#pragma unroll
    for (int j = 0; j < 4; j++) acc[i][j] = (f32x4)0.0f;

  for (int k0 = 0; k0 < K; k0 += 32) {
    __syncthreads();
#pragma unroll
    for (int s = 0; s < 2; s++) {
      const int rbase = s*64 + w*16;
      async_load16(A  + (size_t)(m0 + rbase + lrow)*K + k0 + lcol, As + rbase*32);
      async_load16(Bw + (size_t)(n0 + rbase + lrow)*K + k0 + lcol, Bs + rbase*32);
    }
    __syncthreads();
    bf16x8 af[4], bfr[4];
#pragma unroll
    for (int i = 0; i < 4; i++) {
      af[i]  = *(const bf16x8*)(As + (wm + i*16 + fr)*32 + fg*8);
      bfr[i] = *(const bf16x8*)(Bs + (wn + i*16 + fr)*32 + fg*8);
    }
#pragma unroll
    for (int i = 0; i < 4; i++)
#pragma unroll
      for (int j = 0; j < 4; j++)
        acc[i][j] = __builtin_amdgcn_mfma_f32_16x16x32_bf16(af[i], bfr[j], acc[i][j], 0, 0, 0);
  }

#pragma unroll
  for (int i = 0; i < 4; i++) {
    const int row = m0 + wm + i*16 + fg*4;
#pragma unroll
    for (int j = 0; j < 4; j++) {
      const int col = n0 + wn + j*16 + fr;
#pragma unroll
      for (int r = 0; r < 4; r++) {
        if (OUTMODE == 1) {
          ((float*)C)[(size_t)(row + r)*N + col] = acc[i][j][r];
        } else if (OUTMODE == 0) {
          ((unsigned short*)C)[(size_t)(row + r)*N + col] = f2bf(acc[i][j][r]);
        } else {
          const int rr = row + r;
          const int b = rr >> 11, s = rr & 2047;
          const int h = col >> 7, d = col & 127;
          ((unsigned short*)C)[(((size_t)(b*H_ + h) << 11) + s)*D_ + d] = f2bf(acc[i][j][r]);
        }
      }
    }
  }
}

// xpos rotary, in place on head-major bf16 Q and K [b,h,s,d].
__global__ __launch_bounds__(256)
void xpos_rotary(__hip_bfloat16* __restrict__ Q, __hip_bfloat16* __restrict__ Kt)
{
  const int idx = blockIdx.x * 256 + threadIdx.x;   // [0, B*H*S*64)
  const int j = idx & 63;
  const int s = (idx >> 6) & 2047;
  const float seq = (float)(s - 1024) * (1.0f/512.0f);
  const float dr = 2.0f + 2.0f*(float)j;
  const float theta = expf(dr * (1.0f/128.0f) * -9.210340371976184f);
  const float zeta  = (dr * (1.0f/64.0f) + 51.2f) * (1.0f/52.2f);
  const float ang = seq * theta;
  const float c  = cosf(ang);
  const float sn = sinf(ang);
  const float t  = expf(seq * logf(zeta));
  const float it = 1.0f / t;

  const size_t base = (size_t)(idx >> 6) * 128 + 2*j;
  unsigned short* Qs = (unsigned short*)Q;
  unsigned short* Ks = (unsigned short*)Kt;
  const float q0 = __bfloat162float(Q[base]),  q1 = __bfloat162float(Q[base+1]);
  Qs[base]   = f2bf((q0*c - q1*sn) * t);
  Qs[base+1] = f2bf((q1*c + q0*sn) * t);
  const float k0 = __bfloat162float(Kt[base]), k1 = __bfloat162float(Kt[base+1]);
  Ks[base]   = f2bf((k0*c - k1*sn) * it);
  Ks[base+1] = f2bf((k1*c + k0*sn) * it);
}

// Vh [b,h,s,d] bf16 -> VT3 packed f16:
// per (bh, kt=s/64) 16-KB tile, inner offset = d*64 + g*16 + half*8 + s1*4 + r
// where key=s%64 = (half*2+s1)*16 + g*4 + r. This makes the PV A-fragment
// batch for a 32-key pair ONE contiguous 16-B load per t (fully coalesced).
__global__ __launch_bounds__(256)
void transpose_v(const __hip_bfloat16* __restrict__ Vh, _Float16* __restrict__ VT3)
{
  __shared__ float tile[32][33];
  const int tx = threadIdx.x, ty = threadIdx.y;      // block (32, 8)
  const int bh = blockIdx.z;
  const int s0 = blockIdx.x * 32, d0 = blockIdx.y * 32;
  const int kt = s0 >> 6, koff = s0 & 63;
#pragma unroll
  for (int r = 0; r < 4; r++) {
    const int s = s0 + ty + r*8;
    tile[ty + r*8][tx] = __bfloat162float(Vh[((size_t)bh*S_ + s)*D_ + d0 + tx]);
  }
  __syncthreads();
  const int key = koff + tx;
  const int g = (key >> 2) & 3, rr = key & 3, half = (key >> 5) & 1, s1 = (key >> 4) & 1;
  const size_t base = (size_t)bh*S_*D_ + (size_t)kt*8192 + g*16 + half*8 + s1*4 + rr;
#pragma unroll
  for (int r = 0; r < 4; r++) {
    const int d = d0 + ty + r*8;
    VT3[base + d*64] = (_Float16)tile[tx][ty + r*8];
  }
}

// Flash attention, causal. Independent waves, 32-key iterations (two 16-key
// subtiles, one merged online-softmax pass). __launch_bounds__(256,3) gives
// the allocator ~170 VGPRs so ALL 16 loads per iteration stay in flight
// (R2-R4 at 64-84 VGPRs serialized loads -> ~680us latency wall).
// Head-major Q/K (16-key K tile = contiguous 4 KB); V packed per 64-key tile
// so each t-fragment pair is one 16-B coalesced load. S^T = K*Q^T so the QK
// C-layout (row=key,col=q) is directly the PV B-operand layout.
__global__ __launch_bounds__(256, 3)
void attn_fwd(const __hip_bfloat16* __restrict__ Qh,
              const __hip_bfloat16* __restrict__ Kh,
              const _Float16* __restrict__ VT3,
              __hip_bfloat16* __restrict__ O)
{
  __shared__ float smem_f[64*132];     // padded stride 132: no 16-way conflicts
  const int lane = threadIdx.x & 63;
  const int w    = threadIdx.x >> 6;
  const int bh = blockIdx.y;
  const int b = bh >> 4, h = bh & 15;
  const int x  = gridDim.x - 1 - blockIdx.x;   // longest-first
  const int q0 = x*64 + w*16;
  const int qc = lane & 15;
  const int g  = lane >> 4;
  const int qv = q0 + qc;

  const __hip_bfloat16* Kb = Kh + (size_t)bh*S_*D_;
  const _Float16* vtb = VT3 + (size_t)bh*S_*D_;

  bf16x8 qf[4];
  {
    const __hip_bfloat16* qrow = Qh + ((size_t)bh*S_ + qv)*D_ + g*8;
#pragma unroll
    for (int c = 0; c < 4; c++) qf[c] = *(const bf16x8*)(qrow + c*32);
  }

  f32x4 acc_o[8];
#pragma unroll
  for (int t = 0; t < 8; t++) acc_o[t] = (f32x4)0.0f;
  float m_i = -1e30f, l_i = 0.0f;
  const float scale = 0.08838834764831845f;   // 1/sqrt(128)

  const int nt = x*4 + w + 1;          // 16-key tiles for this wave
  const int np = nt >> 1;              // full 32-key pairs
  for (int kt = 0; kt < np; ++kt) {
    const int k0 = kt*32;
    const __hip_bfloat16* krA = Kb + (size_t)(k0 + qc)*D_ + g*8;
    bf16x8 kfA[4], kfB[4];
#pragma unroll
    for (int c = 0; c < 4; c++) {
      kfA[c] = *(const bf16x8*)(krA + c*32);
      kfB[c] = *(const bf16x8*)(krA + 16*D_ + c*32);
    }
    const _Float16* vp = vtb + (size_t)(kt >> 1)*8192 + (size_t)qc*64 + g*16 + (kt & 1)*8;
    f16x8 vf[8];
#pragma unroll
    for (int t = 0; t < 8; t++) vf[t] = *(const f16x8*)(vp + t*1024);

    f32x4 sA = (f32x4)0.0f, sB = (f32x4)0.0f;
#pragma unroll
    for (int c = 0; c < 4; c++) {
      sA = __builtin_amdgcn_mfma_f32_16x16x32_bf16(kfA[c], qf[c], sA, 0, 0, 0);
      sB = __builtin_amdgcn_mfma_f32_16x16x32_bf16(kfB[c], qf[c], sB, 0, 0, 0);
    }
    float sv[8];
#pragma unroll
    for (int r = 0; r < 4; r++) {
      sv[r]   = (k0      + g*4 + r <= qv) ? sA[r]*scale : -1e30f;
      sv[4+r] = (k0 + 16 + g*4 + r <= qv) ? sB[r]*scale : -1e30f;
    }
    float mx = sv[0];
#pragma unroll
    for (int j = 1; j < 8; j++) mx = fmaxf(mx, sv[j]);
    mx = fmaxf(mx, __shfl_xor(mx, 16));
    mx = fmaxf(mx, __shfl_xor(mx, 32));
    const float m_new = fmaxf(m_i, mx);
    const float alpha = __expf(m_i - m_new);
    float p[8], ps = 0.0f;
#pragma unroll
    for (int j = 0; j < 8; j++) { p[j] = __expf(sv[j] - m_new); ps += p[j]; }
    ps += __shfl_xor(ps, 16);
    ps += __shfl_xor(ps, 32);
    l_i = l_i*alpha + ps;
    m_i = m_new;
    f16x4 pA, pB;
#pragma unroll
    for (int r = 0; r < 4; r++) { pA[r] = (_Float16)p[r]; pB[r] = (_Float16)p[4+r]; }
#pragma unroll
    for (int t = 0; t < 8; t++) acc_o[t] *= alpha;
#pragma unroll
    for (int t = 0; t < 8; t++) {
      const f16x4 vA = __builtin_shufflevector(vf[t], vf[t], 0, 1, 2, 3);
      const f16x4 vB = __builtin_shufflevector(vf[t], vf[t], 4, 5, 6, 7);
      acc_o[t] = __builtin_amdgcn_mfma_f32_16x16x16f16(vA, pA, acc_o[t], 0, 0, 0);
      acc_o[t] = __builtin_amdgcn_mfma_f32_16x16x16f16(vB, pB, acc_o[t], 0, 0, 0);
    }
  }
  if (nt & 1) {   // tail: single (diagonal) 16-key subtile
    const int st = nt - 1;
    const __hip_bfloat16* kr = Kb + (size_t)(st*16 + qc)*D_ + g*8;
    bf16x8 kf[4];
#pragma unroll
    for (int c = 0; c < 4; c++) kf[c] = *(const bf16x8*)(kr + c*32);
    const _Float16* vp = vtb + (size_t)(st >> 2)*8192 + (size_t)qc*64 + g*16
                       + ((st >> 1) & 1)*8 + (st & 1)*4;
    f16x4 vf[8];
#pragma unroll
    for (int t = 0; t < 8; t++) vf[t] = *(const f16x4*)(vp + t*1024);
    f32x4 sA = (f32x4)0.0f;
#pragma unroll
    for (int c = 0; c < 4; c++)
      sA = __builtin_amdgcn_mfma_f32_16x16x32_bf16(kf[c], qf[c], sA, 0, 0, 0);
    float sv[4];
#pragma unroll
    for (int r = 0; r < 4; r++)
      sv[r] = (st*16 + g*4 + r <= qv) ? sA[r]*scale : -1e30f;
    float mx = fmaxf(fmaxf(sv[0], sv[1]), fmaxf(sv[2], sv[3]));
    mx = fmaxf(mx, __shfl_xor(mx, 16));
    mx = fmaxf(mx, __shfl_xor(mx, 32));
    const float m_new = fmaxf(m_i, mx);
    const float alpha = __expf(m_i - m_new);
    float p[4], ps = 0.0f;
#pragma unroll
    for (int j = 0; j < 4; j++) { p[j] = __expf(sv[j] - m_new); ps += p[j]; }
    ps += __shfl_xor(ps, 16);
    ps += __shfl_xor(ps, 32);
    l_i = l_i*alpha + ps;
    m_i = m_new;
    f16x4 pf;
#pragma unroll
    for (int r = 0; r < 4; r++) pf[r] = (_Float16)p[r];
#pragma unroll
    for (int t = 0; t < 8; t++) {
      acc_o[t] *= alpha;
      acc_o[t] = __builtin_amdgcn_mfma_f32_16x16x16f16(vf[t], pf, acc_o[t], 0, 0, 0);
    }
  }

  // epilogue: O^T[d][q] -> LDS as O[q][d] (stride 132), coalesced bf16 store
  __syncthreads();
  const float inv_l = 1.0f / l_i;
#pragma unroll
  for (int t = 0; t < 8; t++)
#pragma unroll
    for (int r = 0; r < 4; r++)
      smem_f[(w*16 + qc)*132 + t*16 + g*4 + r] = acc_o[t][r] * inv_l;
  __syncthreads();

  const int row = threadIdx.x >> 2;          // 0..63
  const int c0  = (threadIdx.x & 3) * 32;
  unsigned short* Os = (unsigned short*)O;
  const size_t obase = ((size_t)b*S_ + x*64 + row)*E_ + h*D_;
#pragma unroll
  for (int i = 0; i < 8; i++) {
    const f32x4 v4 = *(const f32x4*)(smem_f + row*132 + c0 + i*4);
    u16x4 o4;
    o4.x = f2bf(v4.x); o4.y = f2bf(v4.y); o4.z = f2bf(v4.z); o4.w = f2bf(v4.w);
    *(u16x4*)(Os + obase + c0 + i*4) = o4;
  }
}

extern "C" void kernel_launch(void* const* d_in, const int* in_sizes, int n_in,
                              void* d_out, int out_size, void* d_ws, size_t ws_size,
                              hipStream_t stream)
{
  (void)in_sizes; (void)n_in; (void)out_size; (void)ws_size;
  const float* act = (const float*)d_in[0];
  const float* Wq  = (const float*)d_in[1];
  const float* Wk  = (const float*)d_in[2];
  const float* Wv  = (const float*)d_in[3];
  const float* Wo  = (const float*)d_in[4];

  __hip_bfloat16* actb = (__hip_bfloat16*)d_ws;
  __hip_bfloat16* Wqb  = actb + ELEMS;
  __hip_bfloat16* Wkb  = Wqb + WELEMS;
  __hip_bfloat16* Wvb  = Wkb + WELEMS;
  __hip_bfloat16* Wob  = Wvb + WELEMS;
  __hip_bfloat16* Q    = Wob + WELEMS;
  __hip_bfloat16* Kp   = Q + ELEMS;
  __hip_bfloat16* V    = Kp + ELEMS;
  _Float16*       VT   = (_Float16*)(V + ELEMS);
  __hip_bfloat16* AO   = V;   // V dead after transpose_v; reuse for attn output

  cvt_f32_bf16<<<ELEMS/4/256, 256, 0, stream>>>(act, (unsigned short*)actb, ELEMS/4);
  cvt4_f32_bf16<<<dim3(WELEMS/4/256, 4), 256, 0, stream>>>(
      Wq, Wk, Wv, Wo,
      (unsigned short*)Wqb, (unsigned short*)Wkb,
      (unsigned short*)Wvb, (unsigned short*)Wob, WELEMS/4);

  const dim3 gg(E_/128, (B_*S_)/128);
  gemm_bt<2><<<gg, 256, 0, stream>>>(actb, Wqb, Q,  B_*S_, E_, E_);   // head-major
  gemm_bt<2><<<gg, 256, 0, stream>>>(actb, Wkb, Kp, B_*S_, E_, E_);   // head-major
  gemm_bt<2><<<gg, 256, 0, stream>>>(actb, Wvb, V,  B_*S_, E_, E_);   // head-major
  xpos_rotary<<<(B_*S_*H_*64)/256, 256, 0, stream>>>(Q, Kp);
  transpose_v<<<dim3(S_/32, D_/32, B_*H_), dim3(32, 8), 0, stream>>>(V, VT);
  attn_fwd<<<dim3(S_/64, B_*H_), 256, 0, stream>>>(Q, Kp, VT, AO);
  gemm_bt<1><<<gg, 256, 0, stream>>>(AO, Wob, d_out, B_*S_, E_, E_);
}

// Round 6
// 622.918 us; speedup vs baseline: 1.7485x; 1.3311x over previous
//
#include <hip/hip_runtime.h>
#include <hip/hip_bf16.h>

typedef __attribute__((ext_vector_type(8))) short bf16x8;
typedef __attribute__((ext_vector_type(4))) float f32x4;
typedef __attribute__((ext_vector_type(4))) _Float16 f16x4;
typedef __attribute__((ext_vector_type(8))) _Float16 f16x8;
typedef __attribute__((ext_vector_type(4))) unsigned short u16x4;

#define B_ 2
#define S_ 2048
#define E_ 2048
#define H_ 16
#define D_ 128
#define ELEMS (B_*S_*E_)   // 8388608 elements of [B,S,2048]
#define WELEMS (E_*E_)     // 4194304 elements per weight matrix

__device__ __forceinline__ unsigned short f2bf(float x) {
  unsigned int u = __float_as_uint(x);
  u += 0x7fffu + ((u >> 16) & 1u);
  return (unsigned short)(u >> 16);
}

__device__ __forceinline__ void async_load16(const void* g, void* l) {
  __builtin_amdgcn_global_load_lds(
      (const __attribute__((address_space(1))) unsigned int*)g,
      (__attribute__((address_space(3))) unsigned int*)l, 16, 0, 0);
}

// f32 -> bf16 (RNE), vectorized x4. n4 = n/4.
__global__ __launch_bounds__(256)
void cvt_f32_bf16(const float* __restrict__ src, unsigned short* __restrict__ dst, int n4)
{
  const int i = blockIdx.x * 256 + threadIdx.x;
  if (i < n4) {
    const f32x4 v = ((const f32x4*)src)[i];
    u16x4 o;
    o.x = f2bf(v.x); o.y = f2bf(v.y); o.z = f2bf(v.z); o.w = f2bf(v.w);
    ((u16x4*)dst)[i] = o;
  }
}

// four equally-sized weight tensors in one launch (blockIdx.y selects)
__global__ __launch_bounds__(256)
void cvt4_f32_bf16(const float* __restrict__ s0, const float* __restrict__ s1,
                   const float* __restrict__ s2, const float* __restrict__ s3,
                   unsigned short* __restrict__ d0, unsigned short* __restrict__ d1,
                   unsigned short* __restrict__ d2, unsigned short* __restrict__ d3,
                   int n4)
{
  const int i = blockIdx.x * 256 + threadIdx.x;
  if (i >= n4) return;
  const float* s; unsigned short* d;
  switch (blockIdx.y) {
    case 0: s = s0; d = d0; break;
    case 1: s = s1; d = d1; break;
    case 2: s = s2; d = d2; break;
    default: s = s3; d = d3; break;
  }
  const f32x4 v = ((const f32x4*)s)[i];
  u16x4 o;
  o.x = f2bf(v.x); o.y = f2bf(v.y); o.z = f2bf(v.z); o.w = f2bf(v.w);
  ((u16x4*)d)[i] = o;
}

// C[m][n] = sum_k A[m][k] * Bw[n][k]   (torch Linear / B^T layout), bf16 in,
// f32 accumulate. OUTMODE: 0 = bf16 row-major, 1 = f32 row-major,
// 2 = bf16 head-major [b, h, s, d] (row=b*2048+s, col=h*128+d).
template<int OUTMODE>
__global__ __launch_bounds__(256)
void gemm_bt(const __hip_bfloat16* __restrict__ A,
             const __hip_bfloat16* __restrict__ Bw,
             void* __restrict__ C, int M, int N, int K)
{
  __shared__ __hip_bfloat16 As[128*32];
  __shared__ __hip_bfloat16 Bs[128*32];
  const int tid  = threadIdx.x;
  const int lane = tid & 63;
  const int w    = tid >> 6;
  const int m0 = blockIdx.y * 128;
  const int n0 = blockIdx.x * 128;
  const int wm = (w >> 1) * 64;
  const int wn = (w & 1) * 64;
  const int lrow = lane >> 2;
  const int lcol = (lane & 3) * 8;
  const int fr = lane & 15;
  const int fg = lane >> 4;

  f32x4 acc[4][4];
#pragma unroll
  for (int i = 0; i < 4; i++)
#pragma unroll
    for (int j = 0; j < 4; j++) acc[i][j] = (f32x4)0.0f;

  for (int k0 = 0; k0 < K; k0 += 32) {
    __syncthreads();
#pragma unroll
    for (int s = 0; s < 2; s++) {
      const int rbase = s*64 + w*16;
      async_load16(A  + (size_t)(m0 + rbase + lrow)*K + k0 + lcol, As + rbase*32);
      async_load16(Bw + (size_t)(n0 + rbase + lrow)*K + k0 + lcol, Bs + rbase*32);
    }
    __syncthreads();
    bf16x8 af[4], bfr[4];
#pragma unroll
    for (int i = 0; i < 4; i++) {
      af[i]  = *(const bf16x8*)(As + (wm + i*16 + fr)*32 + fg*8);
      bfr[i] = *(const bf16x8*)(Bs + (wn + i*16 + fr)*32 + fg*8);
    }
#pragma unroll
    for (int i = 0; i < 4; i++)
#pragma unroll
      for (int j = 0; j < 4; j++)
        acc[i][j] = __builtin_amdgcn_mfma_f32_16x16x32_bf16(af[i], bfr[j], acc[i][j], 0, 0, 0);
  }

#pragma unroll
  for (int i = 0; i < 4; i++) {
    const int row = m0 + wm + i*16 + fg*4;
#pragma unroll
    for (int j = 0; j < 4; j++) {
      const int col = n0 + wn + j*16 + fr;
#pragma unroll
      for (int r = 0; r < 4; r++) {
        if (OUTMODE == 1) {
          ((float*)C)[(size_t)(row + r)*N + col] = acc[i][j][r];
        } else if (OUTMODE == 0) {
          ((unsigned short*)C)[(size_t)(row + r)*N + col] = f2bf(acc[i][j][r]);
        } else {
          const int rr = row + r;
          const int b = rr >> 11, s = rr & 2047;
          const int h = col >> 7, d = col & 127;
          ((unsigned short*)C)[(((size_t)(b*H_ + h) << 11) + s)*D_ + d] = f2bf(acc[i][j][r]);
        }
      }
    }
  }
}

// xpos rotary, in place on head-major bf16 Q and K [b,h,s,d].
__global__ __launch_bounds__(256)
void xpos_rotary(__hip_bfloat16* __restrict__ Q, __hip_bfloat16* __restrict__ Kt)
{
  const int idx = blockIdx.x * 256 + threadIdx.x;   // [0, B*H*S*64)
  const int j = idx & 63;
  const int s = (idx >> 6) & 2047;
  const float seq = (float)(s - 1024) * (1.0f/512.0f);
  const float dr = 2.0f + 2.0f*(float)j;
  const float theta = expf(dr * (1.0f/128.0f) * -9.210340371976184f);
  const float zeta  = (dr * (1.0f/64.0f) + 51.2f) * (1.0f/52.2f);
  const float ang = seq * theta;
  const float c  = cosf(ang);
  const float sn = sinf(ang);
  const float t  = expf(seq * logf(zeta));
  const float it = 1.0f / t;

  const size_t base = (size_t)(idx >> 6) * 128 + 2*j;
  unsigned short* Qs = (unsigned short*)Q;
  unsigned short* Ks = (unsigned short*)Kt;
  const float q0 = __bfloat162float(Q[base]),  q1 = __bfloat162float(Q[base+1]);
  Qs[base]   = f2bf((q0*c - q1*sn) * t);
  Qs[base+1] = f2bf((q1*c + q0*sn) * t);
  const float k0 = __bfloat162float(Kt[base]), k1 = __bfloat162float(Kt[base+1]);
  Ks[base]   = f2bf((k0*c - k1*sn) * it);
  Ks[base+1] = f2bf((k1*c + k0*sn) * it);
}

// Vh [b,h,s,d] bf16 -> VT3 packed f16:
// per (bh, kt=s/64) 16-KB tile, inner offset = d*64 + g*16 + half*8 + s1*4 + r
// where key=s%64 = (half*2+s1)*16 + g*4 + r.
__global__ __launch_bounds__(256)
void transpose_v(const __hip_bfloat16* __restrict__ Vh, _Float16* __restrict__ VT3)
{
  __shared__ float tile[32][33];
  const int tx = threadIdx.x, ty = threadIdx.y;      // block (32, 8)
  const int bh = blockIdx.z;
  const int s0 = blockIdx.x * 32, d0 = blockIdx.y * 32;
  const int kt = s0 >> 6, koff = s0 & 63;
#pragma unroll
  for (int r = 0; r < 4; r++) {
    const int s = s0 + ty + r*8;
    tile[ty + r*8][tx] = __bfloat162float(Vh[((size_t)bh*S_ + s)*D_ + d0 + tx]);
  }
  __syncthreads();
  const int key = koff + tx;
  const int g = (key >> 2) & 3, rr = key & 3, half = (key >> 5) & 1, s1 = (key >> 4) & 1;
  const size_t base = (size_t)bh*S_*D_ + (size_t)kt*8192 + g*16 + half*8 + s1*4 + rr;
#pragma unroll
  for (int r = 0; r < 4; r++) {
    const int d = d0 + ty + r*8;
    VT3[base + d*64] = (_Float16)tile[tx][ty + r*8];
  }
}

// Flash attention, causal. 32-key pair iterations with explicit ping-pong
// register double-buffering (prefetch pair kt+1 during compute of kt) so
// loads overlap compute instead of serializing at HBM latency (R5: 64-VGPR
// schedule -> ~17k cyc/iter). launch_bounds(256,2) allows ~256 VGPRs.
// XCD pinning: 1-D grid, all 32 q-blocks of one bh on one XCD so K/V stay
// L2-resident (per-XCD hot set 4 bh x 1 MB = 4 MB = L2 size).
__global__ __launch_bounds__(256, 2)
void attn_fwd(const __hip_bfloat16* __restrict__ Qh,
              const __hip_bfloat16* __restrict__ Kh,
              const _Float16* __restrict__ VT3,
              __hip_bfloat16* __restrict__ O)
{
  __shared__ float smem_f[64*132];     // padded stride 132: no 16-way conflicts
  const int lane = threadIdx.x & 63;
  const int w    = threadIdx.x >> 6;
  const int L  = blockIdx.x;                   // 0..1023
  const int bh = (L & 7) + 8*((L >> 3) & 3);   // bh pinned to XCD = bh&7
  const int x  = 31 - (L >> 5);                // longest-first
  const int b = bh >> 4, h = bh & 15;
  const int q0 = x*64 + w*16;
  const int qc = lane & 15;
  const int g  = lane >> 4;
  const int qv = q0 + qc;

  const __hip_bfloat16* Kb = Kh + (size_t)bh*S_*D_;
  const _Float16* vtb = VT3 + (size_t)bh*S_*D_;

  bf16x8 qf[4];
  {
    const __hip_bfloat16* qrow = Qh + ((size_t)bh*S_ + qv)*D_ + g*8;
#pragma unroll
    for (int c = 0; c < 4; c++) qf[c] = *(const bf16x8*)(qrow + c*32);
  }

  f32x4 acc_o[8];
#pragma unroll
  for (int t = 0; t < 8; t++) acc_o[t] = (f32x4)0.0f;
  float m_i = -1e30f, l_i = 0.0f;
  const float scale = 0.08838834764831845f;   // 1/sqrt(128)

  const int nt = x*4 + w + 1;          // 16-key tiles for this wave
  const int np = nt >> 1;              // full 32-key pairs

  // ping-pong register buffers
  bf16x8 ka0[4], kb0[4], ka1[4], kb1[4];
  f16x8  v0[8], v1[8];

#define ISSUE_LOAD(KA, KB, VV, PAIR) do {                                        \
    const __hip_bfloat16* kr_ = Kb + (size_t)((PAIR)*32 + qc)*D_ + g*8;          \
    _Pragma("unroll")                                                            \
    for (int c = 0; c < 4; c++) {                                                \
      KA[c] = *(const bf16x8*)(kr_ + c*32);                                      \
      KB[c] = *(const bf16x8*)(kr_ + 16*D_ + c*32);                              \
    }                                                                            \
    const _Float16* vp_ = vtb + (size_t)((PAIR) >> 1)*8192 + (size_t)qc*64       \
                        + g*16 + ((PAIR) & 1)*8;                                 \
    _Pragma("unroll")                                                            \
    for (int t = 0; t < 8; t++) VV[t] = *(const f16x8*)(vp_ + t*1024);           \
  } while (0)

#define COMPUTE(KA, KB, VV, PAIR) do {                                           \
    const int k0_ = (PAIR)*32;                                                   \
    f32x4 sA = (f32x4)0.0f, sB = (f32x4)0.0f;                                    \
    _Pragma("unroll")                                                            \
    for (int c = 0; c < 4; c++) {                                                \
      sA = __builtin_amdgcn_mfma_f32_16x16x32_bf16(KA[c], qf[c], sA, 0, 0, 0);   \
      sB = __builtin_amdgcn_mfma_f32_16x16x32_bf16(KB[c], qf[c], sB, 0, 0, 0);   \
    }                                                                            \
    float sv[8];                                                                 \
    _Pragma("unroll")                                                            \
    for (int r = 0; r < 4; r++) {                                                \
      sv[r]   = (k0_      + g*4 + r <= qv) ? sA[r]*scale : -1e30f;               \
      sv[4+r] = (k0_ + 16 + g*4 + r <= qv) ? sB[r]*scale : -1e30f;               \
    }                                                                            \
    float mx = sv[0];                                                            \
    _Pragma("unroll")                                                            \
    for (int j = 1; j < 8; j++) mx = fmaxf(mx, sv[j]);                           \
    mx = fmaxf(mx, __shfl_xor(mx, 16));                                          \
    mx = fmaxf(mx, __shfl_xor(mx, 32));                                          \
    const float m_new = fmaxf(m_i, mx);                                          \
    const float alpha = __expf(m_i - m_new);                                     \
    float p[8], ps = 0.0f;                                                       \
    _Pragma("unroll")                                                            \
    for (int j = 0; j < 8; j++) { p[j] = __expf(sv[j] - m_new); ps += p[j]; }    \
    ps += __shfl_xor(ps, 16);                                                    \
    ps += __shfl_xor(ps, 32);                                                    \
    l_i = l_i*alpha + ps;                                                        \
    m_i = m_new;                                                                 \
    f16x4 pA, pB;                                                                \
    _Pragma("unroll")                                                            \
    for (int r = 0; r < 4; r++) { pA[r] = (_Float16)p[r]; pB[r] = (_Float16)p[4+r]; } \
    _Pragma("unroll")                                                            \
    for (int t = 0; t < 8; t++) acc_o[t] *= alpha;                               \
    _Pragma("unroll")                                                            \
    for (int t = 0; t < 8; t++) {                                                \
      const f16x4 vA = __builtin_shufflevector(VV[t], VV[t], 0, 1, 2, 3);        \
      const f16x4 vB = __builtin_shufflevector(VV[t], VV[t], 4, 5, 6, 7);        \
      acc_o[t] = __builtin_amdgcn_mfma_f32_16x16x16f16(vA, pA, acc_o[t], 0, 0, 0); \
      acc_o[t] = __builtin_amdgcn_mfma_f32_16x16x16f16(vB, pB, acc_o[t], 0, 0, 0); \
    }                                                                            \
  } while (0)

  if (np > 0) ISSUE_LOAD(ka0, kb0, v0, 0);
  int kt = 0;
  while (kt + 2 <= np) {
    ISSUE_LOAD(ka1, kb1, v1, kt+1);
    COMPUTE(ka0, kb0, v0, kt);
    if (kt + 2 < np) ISSUE_LOAD(ka0, kb0, v0, kt+2);
    COMPUTE(ka1, kb1, v1, kt+1);
    kt += 2;
  }
  if (kt < np) COMPUTE(ka0, kb0, v0, kt);   // odd-np last pair (already loaded)

  if (nt & 1) {   // tail: single (diagonal) 16-key subtile
    const int st = nt - 1;
    const __hip_bfloat16* kr = Kb + (size_t)(st*16 + qc)*D_ + g*8;
    bf16x8 kf[4];
#pragma unroll
    for (int c = 0; c < 4; c++) kf[c] = *(const bf16x8*)(kr + c*32);
    const _Float16* vp = vtb + (size_t)(st >> 2)*8192 + (size_t)qc*64 + g*16
                       + ((st >> 1) & 1)*8 + (st & 1)*4;
    f16x4 vf[8];
#pragma unroll
    for (int t = 0; t < 8; t++) vf[t] = *(const f16x4*)(vp + t*1024);
    f32x4 sA = (f32x4)0.0f;
#pragma unroll
    for (int c = 0; c < 4; c++)
      sA = __builtin_amdgcn_mfma_f32_16x16x32_bf16(kf[c], qf[c], sA, 0, 0, 0);
    float sv[4];
#pragma unroll
    for (int r = 0; r < 4; r++)
      sv[r] = (st*16 + g*4 + r <= qv) ? sA[r]*scale : -1e30f;
    float mx = fmaxf(fmaxf(sv[0], sv[1]), fmaxf(sv[2], sv[3]));
    mx = fmaxf(mx, __shfl_xor(mx, 16));
    mx = fmaxf(mx, __shfl_xor(mx, 32));
    const float m_new = fmaxf(m_i, mx);
    const float alpha = __expf(m_i - m_new);
    float p[4], ps = 0.0f;
#pragma unroll
    for (int j = 0; j < 4; j++) { p[j] = __expf(sv[j] - m_new); ps += p[j]; }
    ps += __shfl_xor(ps, 16);
    ps += __shfl_xor(ps, 32);
    l_i = l_i*alpha + ps;
    m_i = m_new;
    f16x4 pf;
#pragma unroll
    for (int r = 0; r < 4; r++) pf[r] = (_Float16)p[r];
#pragma unroll
    for (int t = 0; t < 8; t++) {
      acc_o[t] *= alpha;
      acc_o[t] = __builtin_amdgcn_mfma_f32_16x16x16f16(vf[t], pf, acc_o[t], 0, 0, 0);
    }
  }

  // epilogue: O^T[d][q] -> LDS as O[q][d] (stride 132), coalesced bf16 store
  __syncthreads();
  const float inv_l = 1.0f / l_i;
#pragma unroll
  for (int t = 0; t < 8; t++)
#pragma unroll
    for (int r = 0; r < 4; r++)
      smem_f[(w*16 + qc)*132 + t*16 + g*4 + r] = acc_o[t][r] * inv_l;
  __syncthreads();

  const int row = threadIdx.x >> 2;          // 0..63
  const int c0  = (threadIdx.x & 3) * 32;
  unsigned short* Os = (unsigned short*)O;
  const size_t obase = ((size_t)b*S_ + x*64 + row)*E_ + h*D_;
#pragma unroll
  for (int i = 0; i < 8; i++) {
    const f32x4 v4 = *(const f32x4*)(smem_f + row*132 + c0 + i*4);
    u16x4 o4;
    o4.x = f2bf(v4.x); o4.y = f2bf(v4.y); o4.z = f2bf(v4.z); o4.w = f2bf(v4.w);
    *(u16x4*)(Os + obase + c0 + i*4) = o4;
  }
#undef ISSUE_LOAD
#undef COMPUTE
}

extern "C" void kernel_launch(void* const* d_in, const int* in_sizes, int n_in,
                              void* d_out, int out_size, void* d_ws, size_t ws_size,
                              hipStream_t stream)
{
  (void)in_sizes; (void)n_in; (void)out_size; (void)ws_size;
  const float* act = (const float*)d_in[0];
  const float* Wq  = (const float*)d_in[1];
  const float* Wk  = (const float*)d_in[2];
  const float* Wv  = (const float*)d_in[3];
  const float* Wo  = (const float*)d_in[4];

  __hip_bfloat16* actb = (__hip_bfloat16*)d_ws;
  __hip_bfloat16* Wqb  = actb + ELEMS;
  __hip_bfloat16* Wkb  = Wqb + WELEMS;
  __hip_bfloat16* Wvb  = Wkb + WELEMS;
  __hip_bfloat16* Wob  = Wvb + WELEMS;
  __hip_bfloat16* Q    = Wob + WELEMS;
  __hip_bfloat16* Kp   = Q + ELEMS;
  __hip_bfloat16* V    = Kp + ELEMS;
  _Float16*       VT   = (_Float16*)(V + ELEMS);
  __hip_bfloat16* AO   = V;   // V dead after transpose_v; reuse for attn output

  cvt_f32_bf16<<<ELEMS/4/256, 256, 0, stream>>>(act, (unsigned short*)actb, ELEMS/4);
  cvt4_f32_bf16<<<dim3(WELEMS/4/256, 4), 256, 0, stream>>>(
      Wq, Wk, Wv, Wo,
      (unsigned short*)Wqb, (unsigned short*)Wkb,
      (unsigned short*)Wvb, (unsigned short*)Wob, WELEMS/4);

  const dim3 gg(E_/128, (B_*S_)/128);
  gemm_bt<2><<<gg, 256, 0, stream>>>(actb, Wqb, Q,  B_*S_, E_, E_);   // head-major
  gemm_bt<2><<<gg, 256, 0, stream>>>(actb, Wkb, Kp, B_*S_, E_, E_);   // head-major
  gemm_bt<2><<<gg, 256, 0, stream>>>(actb, Wvb, V,  B_*S_, E_, E_);   // head-major
  xpos_rotary<<<(B_*S_*H_*64)/256, 256, 0, stream>>>(Q, Kp);
  transpose_v<<<dim3(S_/32, D_/32, B_*H_), dim3(32, 8), 0, stream>>>(V, VT);
  attn_fwd<<<1024, 256, 0, stream>>>(Q, Kp, VT, AO);
  gemm_bt<1><<<gg, 256, 0, stream>>>(AO, Wob, d_out, B_*S_, E_, E_);
}